// Round 4
// baseline (69.698 us; speedup 1.0000x reference)
//
#include <hip/hip_runtime.h>
#include <stdint.h>

#define B_  8
#define C_  128
#define N_  8192
#define K_  16
#define O_  128
#define TP  32                       // points per k_main block
#define PL  ((size_t)65536 * 32)     // elems per channel-plane (4 MB)

typedef __attribute__((ext_vector_type(8))) short short8;
typedef __attribute__((ext_vector_type(4))) float f32x4;

__device__ __forceinline__ unsigned short f2bf(float f) {
    union { float f; uint32_t u; } v; v.f = f;
    uint32_t u = v.u;
    return (unsigned short)((u + 0x7FFFu + ((u >> 16) & 1u)) >> 16);  // RNE
}
// Orderable-u16 map for bf16 (monotone bijection; unsigned cmp == float cmp)
__device__ __forceinline__ uint32_t fwdmap(uint32_t u) {
    uint32_t s  = u & 0x80008000u;
    uint32_t xm = s - (s >> 15) + 0x80008000u;
    return u ^ xm;
}
__device__ __forceinline__ uint32_t invmap(uint32_t v) {
    uint32_t s  = (~v) & 0x80008000u;
    uint32_t xm = s - (s >> 15) + 0x80008000u;
    return v ^ xm;
}
__device__ __forceinline__ uint32_t pkmax(uint32_t a, uint32_t b) {
    uint32_t d;
    asm("v_pk_max_u16 %0, %1, %2" : "=v"(d) : "v"(a), "v"(b));
    return d;
}
__device__ __forceinline__ uint2 pkmax2(uint2 a, uint2 b) {
    return make_uint2(pkmax(a.x, b.x), pkmax(a.y, b.y));
}
__device__ __forceinline__ uint2 tree8(const uint2 d[8]) {
    uint2 t0 = pkmax2(d[0], d[4]), t1 = pkmax2(d[1], d[5]);
    uint2 t2 = pkmax2(d[2], d[6]), t3 = pkmax2(d[3], d[7]);
    t0 = pkmax2(t0, t2); t1 = pkmax2(t1, t3);
    return pkmax2(t0, t1);
}

// Kernel 1: x (B,C,N) f32 -> 4 channel-planes xt[pl][B*N][32] of orderable-u16.
// Optional extra block (blk==1024) pre-converts W to bf16 row-major.
template<bool PREW>
__global__ __launch_bounds__(256) void k_transpose(const float* __restrict__ x,
                                                   unsigned short* __restrict__ xt,
                                                   const float* __restrict__ Wp,
                                                   unsigned short* __restrict__ Wbf) {
    int blk = blockIdx.x;
    if (PREW && blk == 1024) {      // W: 128x128 f32 -> bf16 (8192 packed pairs)
        int t = threadIdx.x;
        #pragma unroll
        for (int i = 0; i < 32; ++i) {
            int e = t + i * 256;
            float2 w2 = ((const float2*)Wp)[e];
            ((uint32_t*)Wbf)[e] = (uint32_t)f2bf(w2.x) | ((uint32_t)f2bf(w2.y) << 16);
        }
        return;
    }
    __shared__ uint32_t lds[64 * 66];   // [c2][n_local], stride 66 -> 2-way (free)
    int t    = threadIdx.x;
    int lane = t & 63;
    int wv   = t >> 6;
    int b    = blk >> 7;
    int n0   = (blk & 127) * 64;

    const float* xb = x + (size_t)b * C_ * N_ + n0 + lane;
    #pragma unroll
    for (int j = 0; j < 16; ++j) {
        int c2 = wv * 16 + j;
        float f0 = xb[(size_t)(2 * c2) * N_];
        float f1 = xb[(size_t)(2 * c2 + 1) * N_];
        uint32_t pk = (uint32_t)f2bf(f0) | ((uint32_t)f2bf(f1) << 16);
        lds[c2 * 66 + lane] = fwdmap(pk);
    }
    __syncthreads();

    int rr = lane >> 2;    // row 0..15 within this wave's 16-row strip
    int ch = lane & 3;     // 16B chunk of the 64B plane-row
    size_t rowb = (size_t)(b * N_ + n0);
    #pragma unroll
    for (int pl = 0; pl < 4; ++pl) {
        int r = wv * 16 + rr;
        uint32_t u0 = lds[(pl * 16 + ch * 4 + 0) * 66 + r];
        uint32_t u1 = lds[(pl * 16 + ch * 4 + 1) * 66 + r];
        uint32_t u2 = lds[(pl * 16 + ch * 4 + 2) * 66 + r];
        uint32_t u3 = lds[(pl * 16 + ch * 4 + 3) * 66 + r];
        *(uint4*)(xt + (size_t)pl * PL + (rowb + r) * 32 + ch * 8) =
            make_uint4(u0, u1, u2, u3);
    }
}

// Kernel 2: 32 points/block, grid 2048 (8 blocks/CU, 32 waves/CU).
// Gather per plane (4 MB instantaneous footprint ~= one XCD L2):
// lane = (point 0..7, 8B-chunk 0..7); 2x8 independent uint2 loads + pkmax tree.
// GEMM: wave owns 32 output rows x 32 points.
template<bool PREW>
__global__ __launch_bounds__(256, 8) void k_main(const unsigned short* __restrict__ xt,
                                                 const int* __restrict__ idx,
                                                 const float* __restrict__ Wp,
                                                 const unsigned short* __restrict__ Wbf,
                                                 const float* __restrict__ bp,
                                                 float* __restrict__ out) {
    __shared__ __align__(16) unsigned short agg[TP * 136];  // 8704 B
    __shared__ int idxs[TP * K_];                            // 2048 B

    int t    = threadIdx.x;
    int lane = t & 63;
    int wv   = t >> 6;
    int blk  = blockIdx.x;          // 8 b * 256 ntiles
    int b    = blk >> 8;
    int n0   = (blk & 255) * TP;
    size_t pbase = (size_t)b * N_ + n0;

    // ---- stage idx (512 ints) ----
    const int* ip = idx + pbase * K_;
    idxs[t]       = ip[t];
    idxs[t + 256] = ip[t + 256];
    __syncthreads();

    // ---- gather + max, plane by plane ----
    int pt  = lane >> 3;   // point within wave's 8
    int cch = lane & 7;    // 8B chunk of the 64B plane-row
    int p   = wv * 8 + pt;
    const int* qq = &idxs[p * K_];
    #pragma unroll
    for (int pl = 0; pl < 4; ++pl) {
        const unsigned short* base = xt + (size_t)pl * PL + cch * 4;
        uint2 d[8];
        #pragma unroll
        for (int k = 0; k < 8; ++k)
            d[k] = *(const uint2*)(base + (size_t)qq[k] * 32);
        uint2 r0 = tree8(d);
        #pragma unroll
        for (int k = 0; k < 8; ++k)
            d[k] = *(const uint2*)(base + (size_t)qq[k + 8] * 32);
        uint2 r1 = tree8(d);
        uint2 r  = pkmax2(r0, r1);
        *(uint2*)&agg[p * 136 + pl * 32 + cch * 4] =
            make_uint2(invmap(r.x), invmap(r.y));
    }
    __syncthreads();

    // ---- MFMA GEMM: wave computes o in [wo,wo+32) x 32 points ----
    int r16 = lane & 15;
    int h   = lane >> 4;
    int wo  = wv * 32;
    const size_t ob = (size_t)b * O_ * N_ + n0;

    #pragma unroll
    for (int ot2 = 0; ot2 < 2; ++ot2) {
        short8 af[4];
        if (PREW) {
            #pragma unroll
            for (int kk = 0; kk < 4; ++kk)
                af[kk] = *(const short8*)(Wbf + (size_t)(wo + ot2 * 16 + r16) * C_ + kk * 32 + h * 8);
        } else {
            #pragma unroll
            for (int kk = 0; kk < 4; ++kk) {
                const float* wr = Wp + (size_t)(wo + ot2 * 16 + r16) * C_ + kk * 32 + h * 8;
                float4 a0 = *(const float4*)wr;
                float4 a1 = *(const float4*)(wr + 4);
                short8 s;
                s[0] = (short)f2bf(a0.x); s[1] = (short)f2bf(a0.y);
                s[2] = (short)f2bf(a0.z); s[3] = (short)f2bf(a0.w);
                s[4] = (short)f2bf(a1.x); s[5] = (short)f2bf(a1.y);
                s[6] = (short)f2bf(a1.z); s[7] = (short)f2bf(a1.w);
                af[kk] = s;
            }
        }
        float4 bv = *(const float4*)(bp + wo + ot2 * 16 + h * 4);
        int orow = wo + ot2 * 16 + h * 4;
        #pragma unroll
        for (int pt4 = 0; pt4 < 2; ++pt4) {
            short8 bfr[4];
            #pragma unroll
            for (int kk = 0; kk < 4; ++kk)
                bfr[kk] = *(const short8*)&agg[(pt4 * 16 + r16) * 136 + kk * 32 + h * 8];
            f32x4 acc = {0.f, 0.f, 0.f, 0.f};
            #pragma unroll
            for (int kk = 0; kk < 4; ++kk)
                acc = __builtin_amdgcn_mfma_f32_16x16x32_bf16(af[kk], bfr[kk], acc, 0, 0, 0);
            float* op = out + ob + (size_t)orow * N_ + pt4 * 16 + r16;
            op[0]              = fmaxf(acc[0] + bv.x, 0.f);
            op[(size_t)N_]     = fmaxf(acc[1] + bv.y, 0.f);
            op[(size_t)2 * N_] = fmaxf(acc[2] + bv.z, 0.f);
            op[(size_t)3 * N_] = fmaxf(acc[3] + bv.w, 0.f);
        }
    }
}

extern "C" void kernel_launch(void* const* d_in, const int* in_sizes, int n_in,
                              void* d_out, int out_size, void* d_ws, size_t ws_size,
                              hipStream_t stream) {
    (void)in_sizes; (void)n_in; (void)out_size;
    const float* x    = (const float*)d_in[0];
    const int*   idx  = (const int*)d_in[1];
    const float* W    = (const float*)d_in[2];
    const float* bias = (const float*)d_in[3];
    float* out = (float*)d_out;

    const size_t XTB = (size_t)4 * PL * 2;          // 16 MB of planes
    unsigned short* xt  = (unsigned short*)d_ws;
    unsigned short* wbf = (unsigned short*)((char*)d_ws + XTB);
    bool prew = ws_size >= XTB + O_ * C_ * 2;

    if (prew) {
        hipLaunchKernelGGL(k_transpose<true>,  dim3(1025), dim3(256), 0, stream, x, xt, W, wbf);
        hipLaunchKernelGGL(k_main<true>,       dim3(2048), dim3(256), 0, stream, xt, idx, W, wbf, bias, out);
    } else {
        hipLaunchKernelGGL(k_transpose<false>, dim3(1024), dim3(256), 0, stream, x, xt, W, wbf);
        hipLaunchKernelGGL(k_main<false>,      dim3(2048), dim3(256), 0, stream, xt, idx, W, wbf, bias, out);
    }
}

// Round 5
// 50.137 us; speedup vs baseline: 1.3901x; 1.3901x over previous
//
#include <hip/hip_runtime.h>
#include <stdint.h>

#define B_  8
#define C_  128
#define N_  8192
#define K_  16
#define O_  128
#define TP  32     // points per k_main block -> grid 2048 -> 8 blocks/CU

typedef __attribute__((ext_vector_type(8))) short short8;
typedef __attribute__((ext_vector_type(4))) float f32x4;

__device__ __forceinline__ unsigned short f2bf(float f) {
    union { float f; uint32_t u; } v; v.f = f;
    uint32_t u = v.u;
    return (unsigned short)((u + 0x7FFFu + ((u >> 16) & 1u)) >> 16);  // RNE
}
// Orderable-u16 map for bf16 (monotone bijection; unsigned cmp == float cmp)
__device__ __forceinline__ uint32_t fwdmap(uint32_t u) {
    uint32_t s  = u & 0x80008000u;
    uint32_t xm = s - (s >> 15) + 0x80008000u;
    return u ^ xm;
}
__device__ __forceinline__ uint32_t invmap(uint32_t v) {
    uint32_t s  = (~v) & 0x80008000u;
    uint32_t xm = s - (s >> 15) + 0x80008000u;
    return v ^ xm;
}
__device__ __forceinline__ uint32_t pkmax(uint32_t a, uint32_t b) {
    uint32_t d;
    asm("v_pk_max_u16 %0, %1, %2" : "=v"(d) : "v"(a), "v"(b));
    return d;
}
__device__ __forceinline__ uint4 pkmax4(uint4 a, uint4 b) {
    return make_uint4(pkmax(a.x, b.x), pkmax(a.y, b.y),
                      pkmax(a.z, b.z), pkmax(a.w, b.w));
}

// Kernel 1: x (B,C,N) f32 -> xt (B*N, C) orderable-u16 row-major (256B rows).
// Optional extra block (blk==1024) pre-converts W to bf16 row-major.
template<bool PREW>
__global__ __launch_bounds__(256) void k_transpose(const float* __restrict__ x,
                                                   unsigned short* __restrict__ xt,
                                                   const float* __restrict__ Wp,
                                                   unsigned short* __restrict__ Wbf) {
    int blk = blockIdx.x;
    if (PREW && blk == 1024) {      // W: 128x128 f32 -> bf16 (8192 packed pairs)
        int t = threadIdx.x;
        #pragma unroll
        for (int i = 0; i < 32; ++i) {
            int e = t + i * 256;
            float2 w2 = ((const float2*)Wp)[e];
            ((uint32_t*)Wbf)[e] = (uint32_t)f2bf(w2.x) | ((uint32_t)f2bf(w2.y) << 16);
        }
        return;
    }
    __shared__ uint32_t lds[64 * 66];   // [c2][n_local], stride 66 (2-way = free)
    int t    = threadIdx.x;
    int lane = t & 63;
    int wv   = t >> 6;
    int b    = blk >> 7;
    int n0   = (blk & 127) * 64;

    const float* xb = x + (size_t)b * C_ * N_ + n0 + lane;
    #pragma unroll
    for (int j = 0; j < 16; ++j) {
        int c2 = wv * 16 + j;
        float f0 = xb[(size_t)(2 * c2) * N_];
        float f1 = xb[(size_t)(2 * c2 + 1) * N_];
        uint32_t pk = (uint32_t)f2bf(f0) | ((uint32_t)f2bf(f1) << 16);
        lds[c2 * 66 + lane] = fwdmap(pk);
    }
    __syncthreads();

    int rl = lane >> 4;    // row-in-group 0..3
    int ch = lane & 15;    // 16B chunk of the 256B row
    #pragma unroll
    for (int it = 0; it < 4; ++it) {
        int r = it * 16 + wv * 4 + rl;
        uint32_t u0 = lds[(ch * 4 + 0) * 66 + r];
        uint32_t u1 = lds[(ch * 4 + 1) * 66 + r];
        uint32_t u2 = lds[(ch * 4 + 2) * 66 + r];
        uint32_t u3 = lds[(ch * 4 + 3) * 66 + r];
        *(uint4*)(xt + ((size_t)(b * N_ + n0 + r)) * C_ + ch * 8) =
            make_uint4(u0, u1, u2, u3);
    }
}

// Kernel 2: 32 points/block, grid 2048 -> 8 blocks/CU (32 waves/CU).
// Gather: lane = (point-in-group-of-4, 16B chunk); 16 independent uint4 loads
// per point then depth-4 pkmax tree. launch_bounds(256,4) keeps VGPR ~56-64
// so the loads stay in flight (round-4 lesson: (256,8) -> 32 VGPR serialized).
// Out stores non-temporal so the 33.5MB write doesn't evict the gather table.
template<bool PREW>
__global__ __launch_bounds__(256, 4) void k_main(const unsigned short* __restrict__ xt,
                                                 const int* __restrict__ idx,
                                                 const float* __restrict__ Wp,
                                                 const unsigned short* __restrict__ Wbf,
                                                 const float* __restrict__ bp,
                                                 float* __restrict__ out) {
    __shared__ __align__(16) unsigned short agg[TP * 136];  // 8704 B
    __shared__ int idxs[TP * K_];                            // 2048 B

    int t    = threadIdx.x;
    int lane = t & 63;
    int wv   = t >> 6;
    int blk  = blockIdx.x;          // 8 b * 256 ntiles
    int b    = blk >> 8;
    int n0   = (blk & 255) * TP;
    size_t pbase = (size_t)b * N_ + n0;

    // ---- stage idx (512 ints), non-temporal ----
    const int* ip = idx + pbase * K_;
    idxs[t]       = __builtin_nontemporal_load(ip + t);
    idxs[t + 256] = __builtin_nontemporal_load(ip + t + 256);
    __syncthreads();

    // ---- gather + max: 8 points per wave, 4 points per iteration ----
    int pt  = lane >> 4;   // point within group of 4
    int cch = lane & 15;   // 16B chunk of 256B row
    #pragma unroll
    for (int i = 0; i < 2; ++i) {
        int p = wv * 8 + i * 4 + pt;
        const int* qq = &idxs[p * K_];
        uint4 d[16];
        #pragma unroll
        for (int k = 0; k < 16; ++k)
            d[k] = *(const uint4*)(xt + (size_t)qq[k] * C_ + cch * 8);
        #pragma unroll
        for (int s = 8; s >= 1; s >>= 1)
            #pragma unroll
            for (int k = 0; k < s; ++k)
                d[k] = pkmax4(d[k], d[k + s]);
        uint4 v = make_uint4(invmap(d[0].x), invmap(d[0].y),
                             invmap(d[0].z), invmap(d[0].w));
        *(uint4*)&agg[p * 136 + cch * 8] = v;
    }
    __syncthreads();

    // ---- MFMA GEMM: wave computes o in [wo,wo+32) x 32 points ----
    int r16 = lane & 15;
    int h   = lane >> 4;
    int wo  = wv * 32;
    const size_t ob = (size_t)b * O_ * N_ + n0;

    #pragma unroll
    for (int ot2 = 0; ot2 < 2; ++ot2) {
        short8 af[4];
        if (PREW) {
            #pragma unroll
            for (int kk = 0; kk < 4; ++kk)
                af[kk] = *(const short8*)(Wbf + (size_t)(wo + ot2 * 16 + r16) * C_ + kk * 32 + h * 8);
        } else {
            #pragma unroll
            for (int kk = 0; kk < 4; ++kk) {
                const float* wr = Wp + (size_t)(wo + ot2 * 16 + r16) * C_ + kk * 32 + h * 8;
                float4 a0 = *(const float4*)wr;
                float4 a1 = *(const float4*)(wr + 4);
                short8 s;
                s[0] = (short)f2bf(a0.x); s[1] = (short)f2bf(a0.y);
                s[2] = (short)f2bf(a0.z); s[3] = (short)f2bf(a0.w);
                s[4] = (short)f2bf(a1.x); s[5] = (short)f2bf(a1.y);
                s[6] = (short)f2bf(a1.z); s[7] = (short)f2bf(a1.w);
                af[kk] = s;
            }
        }
        float4 bv = *(const float4*)(bp + wo + ot2 * 16 + h * 4);
        int orow = wo + ot2 * 16 + h * 4;
        #pragma unroll
        for (int pt2 = 0; pt2 < 2; ++pt2) {
            short8 bfr[4];
            #pragma unroll
            for (int kk = 0; kk < 4; ++kk)
                bfr[kk] = *(const short8*)&agg[(pt2 * 16 + r16) * 136 + kk * 32 + h * 8];
            f32x4 acc = {0.f, 0.f, 0.f, 0.f};
            #pragma unroll
            for (int kk = 0; kk < 4; ++kk)
                acc = __builtin_amdgcn_mfma_f32_16x16x32_bf16(af[kk], bfr[kk], acc, 0, 0, 0);
            float* op = out + ob + (size_t)orow * N_ + pt2 * 16 + r16;
            __builtin_nontemporal_store(fmaxf(acc[0] + bv.x, 0.f), op);
            __builtin_nontemporal_store(fmaxf(acc[1] + bv.y, 0.f), op + (size_t)N_);
            __builtin_nontemporal_store(fmaxf(acc[2] + bv.z, 0.f), op + (size_t)2 * N_);
            __builtin_nontemporal_store(fmaxf(acc[3] + bv.w, 0.f), op + (size_t)3 * N_);
        }
    }
}

extern "C" void kernel_launch(void* const* d_in, const int* in_sizes, int n_in,
                              void* d_out, int out_size, void* d_ws, size_t ws_size,
                              hipStream_t stream) {
    (void)in_sizes; (void)n_in; (void)out_size;
    const float* x    = (const float*)d_in[0];
    const int*   idx  = (const int*)d_in[1];
    const float* W    = (const float*)d_in[2];
    const float* bias = (const float*)d_in[3];
    float* out = (float*)d_out;

    const size_t XTB = (size_t)B_ * N_ * C_ * 2;    // 16 MB table
    unsigned short* xt  = (unsigned short*)d_ws;
    unsigned short* wbf = (unsigned short*)((char*)d_ws + XTB);
    bool prew = ws_size >= XTB + O_ * C_ * 2;

    if (prew) {
        hipLaunchKernelGGL(k_transpose<true>,  dim3(1025), dim3(256), 0, stream, x, xt, W, wbf);
        hipLaunchKernelGGL(k_main<true>,       dim3(2048), dim3(256), 0, stream, xt, idx, W, wbf, bias, out);
    } else {
        hipLaunchKernelGGL(k_transpose<false>, dim3(1024), dim3(256), 0, stream, x, xt, W, wbf);
        hipLaunchKernelGGL(k_main<false>,      dim3(2048), dim3(256), 0, stream, xt, idx, W, wbf, bias, out);
    }
}